// Round 23
// baseline (57.988 us; speedup 1.0000x reference)
//
#include <hip/hip_runtime.h>
#include <hip/hip_bf16.h>

typedef float f32x4 __attribute__((ext_vector_type(4)));
typedef __bf16 bf16x8 __attribute__((ext_vector_type(8)));

static __device__ __forceinline__ unsigned short f2bf(float f) {
    unsigned int u = __float_as_uint(f);
    unsigned int r = (u + 0x7fffu + ((u >> 16) & 1u)) >> 16;   // RNE
    return (unsigned short)r;
}

// ---------------------------------------------------------------------------
// prep: pack conv weights (tile-major MFMA-ready, coalesced reads) +
// cumsum + idx-expand.  (unchanged, proven)
// ---------------------------------------------------------------------------
__global__ __launch_bounds__(512) void prep(
    const float* __restrict__ w1, const float* __restrict__ w2,
    unsigned short* __restrict__ w1p, unsigned short* __restrict__ w2p,
    const int* __restrict__ tgt, short* __restrict__ idxT, int M)
{
    int blk = blockIdx.x;
    if (blk < 256) {
        int gi = blk * 512 + threadIdx.x;            // pair index (n,cin)
        const float* w = (gi < 65536) ? w1 : w2;
        unsigned short* wp = (gi < 65536) ? w1p : w2p;
        int p = gi & 65535;
        int n = p >> 8, cin = p & 255;
        const float* src = w + (size_t)p * 3;
        float a[3] = {src[0], src[1], src[2]};
        int nb = n >> 4, nl = n & 15;
        int e = cin & 7, lhi = (cin >> 3) & 3, chi = cin >> 5;
        int base = nb * 512 + (lhi * 16 + nl) * 8 + e;
        #pragma unroll
        for (int kk = 0; kk < 3; ++kk)
            wp[(kk * 8 + chi) * 8192 + base] = f2bf(a[kk]);
    } else {
        __shared__ int s[512];
        int b = blk - 256, tid = threadIdx.x;
        int d = tgt[b * 512 + tid];
        s[tid] = d;
        __syncthreads();
        for (int off = 1; off < 512; off <<= 1) {
            int v = (tid >= off) ? s[tid - off] : 0;
            __syncthreads();
            s[tid] += v;
            __syncthreads();
        }
        int myend = s[tid];
        int mystart = myend - d;
        short* row = idxT + (size_t)b * M;
        for (int p = mystart; p < myend; ++p) row[p] = (short)tid;
        __syncthreads();
        int total = s[511];
        for (int p = total + tid; p < M; p += 512) row[p] = (short)-1;
    }
}

// ---------------------------------------------------------------------------
// Fused conv1+conv2, M=96 tiles (output stride 94): 192 conv blocks = single
// block-wave on 256 CUs, amortizing the fixed 48-step W-load chain over 96
// rows.  H[96][256] in LDS (49 KB); As dbuf 12.5 KB; total ~66.3 KB.
// Gather: 1792 blocks (64 mel rows each), unchanged.
// ---------------------------------------------------------------------------
__global__ __launch_bounds__(512, 2) void fused(
    const float* __restrict__ x,
    const unsigned short* __restrict__ w1p, const float* __restrict__ b1,
    const float* __restrict__ g1, const float* __restrict__ be1,
    const unsigned short* __restrict__ w2p, const float* __restrict__ b2,
    const float* __restrict__ g2, const float* __restrict__ be2,
    const float* __restrict__ lw, const float* __restrict__ lb,
    float* __restrict__ dur, const short* __restrict__ idxT,
    float* __restrict__ out, int M)
{
    __shared__ __align__(16) unsigned short H[96 * 256];       // 49,152 B
    __shared__ __align__(16) unsigned short As[2][98 * 32];    // 12,544 B dbuf
    __shared__ float lnS[4][96], lnQ[4][96], lnD[4][96];       //  4,608 B

    const int tid = threadIdx.x;
    const int lane = tid & 63;
    const int wv = tid >> 6;

    if (blockIdx.x >= 192) {
        // ---- gather: 64 rows, idx lookup, plain stores
        int gid = blockIdx.x - 192;
        int b = gid / 56;
        int r0 = (gid - b * 56) * 64;
        const short* row = idxT + (size_t)b * M;
        int id[8];
        #pragma unroll
        for (int i = 0; i < 8; ++i) id[i] = row[r0 + i * 8 + wv];
        #pragma unroll
        for (int i = 0; i < 8; ++i) {
            int m = r0 + i * 8 + wv;
            float4 v = make_float4(0.f, 0.f, 0.f, 0.f);
            if (id[i] >= 0)
                v = *reinterpret_cast<const float4*>(x + ((size_t)(b * 512 + id[i])) * 256 + lane * 4);
            *reinterpret_cast<float4*>(out + ((size_t)b * M + m) * 256 + lane * 4) = v;
        }
        return;
    }

    const int wmi = wv >> 2, wni = wv & 3;
    const int grp = lane >> 4, lr = lane & 15;
    const int b = blockIdx.x / 6;
    const int t0 = (blockIdx.x - b * 6) * 94;     // output window [t0, t0+94)

    // per-lane W-frag base offset (ushorts) within a tile
    const int wfoff = (wni * 4) * 512 + lane * 8;

    #define LOADW(dst, wp, ktg) do {                                           \
        const unsigned short* _p = (wp) + (size_t)(ktg) * 8192 + wfoff;        \
        dst[0] = *reinterpret_cast<const bf16x8*>(_p);                         \
        dst[1] = *reinterpret_cast<const bf16x8*>(_p + 512);                   \
        dst[2] = *reinterpret_cast<const bf16x8*>(_p + 1024);                  \
        dst[3] = *reinterpret_cast<const bf16x8*>(_p + 1536);                  \
    } while (0)

    // stage cin-eighth cb of x window (98 rows: t0-2 .. t0+95) into As[buf]
    #define STAGE_A(cb, buf) do {                                              \
        _Pragma("unroll")                                                      \
        for (int _i = 0; _i < 2; ++_i) {                                       \
            int _cc = _i * 512 + tid;                                          \
            if (_cc < 98 * 8) {                                                \
                int _row = _cc >> 3, _ql = _cc & 7;                            \
                int _tt = t0 - 2 + _row;                                       \
                ushort4 _o = make_ushort4(0, 0, 0, 0);                         \
                if ((unsigned)_tt < 512u) {                                    \
                    float4 _v = *reinterpret_cast<const float4*>(              \
                        x + ((size_t)(b * 512 + _tt)) * 256 + (cb) * 32 + _ql * 4); \
                    _o.x = f2bf(_v.x); _o.y = f2bf(_v.y);                      \
                    _o.z = f2bf(_v.z); _o.w = f2bf(_v.w);                      \
                }                                                              \
                *reinterpret_cast<ushort4*>(                                   \
                    &As[buf][_row * 32 + ((_ql * 4) ^ ((_row & 3) << 3))]) = _o; \
            }                                                                  \
        }                                                                      \
    } while (0)

    // ============ CONV1: h1 frame rows R=0..95 (t = t0-1+R) -> H ============
    f32x4 acc[3][4] = {};
    bf16x8 bw[2][4];                              // 2-deep W-frag pipeline
    STAGE_A(0, 0);
    LOADW(bw[0], w1p, 0);                         // jj=0: kk=0, cb=0 -> ktg 0
    __syncthreads();
    #pragma unroll
    for (int cb = 0; cb < 8; ++cb) {              // cin eighth [cb*32, +32)
        if (cb < 7) STAGE_A(cb + 1, (cb + 1) & 1);   // prefetch next eighth
        #pragma unroll
        for (int kk = 0; kk < 3; ++kk) {
            const int jj = cb * 3 + kk;           // compile-time (both unrolled)
            if (jj < 23) {
                const int jn = jj + 1;
                LOADW(bw[jn & 1], w1p, (jn % 3) * 8 + (jn / 3));
            } else {
                LOADW(bw[0], w2p, 0);             // conv2 tile 0 (hides under epilogue)
            }
            bf16x8 af[3];
            #pragma unroll
            for (int mi = 0; mi < 3; ++mi) {
                int tr = wmi * 48 + mi * 16 + lr + kk;     // As row (<= 97)
                af[mi] = *reinterpret_cast<const bf16x8*>(
                    &As[cb & 1][tr * 32 + ((grp * 8) ^ ((tr & 3) << 3))]);
            }
            #pragma unroll
            for (int mi = 0; mi < 3; ++mi)
                #pragma unroll
                for (int ni = 0; ni < 4; ++ni)
                    acc[mi][ni] = __builtin_amdgcn_mfma_f32_16x16x32_bf16(af[mi], bw[jj & 1][ni], acc[mi][ni], 0, 0, 0);
        }
        __syncthreads();                          // stage(cb+1) stores + As reads done
    }

    // ---- conv1 epilogue: bias+relu, LN, store H (bf16, swizzled, zero-guard)
    {
        float bcol[4], gcol[4], becol[4];
        #pragma unroll
        for (int ni = 0; ni < 4; ++ni) {
            int col = wni * 64 + ni * 16 + lr;
            bcol[ni] = b1[col]; gcol[ni] = g1[col]; becol[ni] = be1[col];
        }
        #pragma unroll
        for (int mi = 0; mi < 3; ++mi)
            #pragma unroll
            for (int ni = 0; ni < 4; ++ni)
                #pragma unroll
                for (int r = 0; r < 4; ++r)
                    acc[mi][ni][r] = fmaxf(acc[mi][ni][r] + bcol[ni], 0.f);

        #pragma unroll
        for (int mi = 0; mi < 3; ++mi)
            #pragma unroll
            for (int r = 0; r < 4; ++r) {
                float s = acc[mi][0][r] + acc[mi][1][r] + acc[mi][2][r] + acc[mi][3][r];
                float q = acc[mi][0][r] * acc[mi][0][r] + acc[mi][1][r] * acc[mi][1][r]
                        + acc[mi][2][r] * acc[mi][2][r] + acc[mi][3][r] * acc[mi][3][r];
                #pragma unroll
                for (int off = 1; off < 16; off <<= 1) {
                    s += __shfl_xor(s, off);
                    q += __shfl_xor(q, off);
                }
                if (lr == 0) {
                    int R = wmi * 48 + mi * 16 + grp * 4 + r;
                    lnS[wni][R] = s; lnQ[wni][R] = q;
                }
            }
        __syncthreads();
        #pragma unroll
        for (int mi = 0; mi < 3; ++mi)
            #pragma unroll
            for (int r = 0; r < 4; ++r) {
                int R = wmi * 48 + mi * 16 + grp * 4 + r;    // h1 row t = t0-1+R
                int t = t0 - 1 + R;
                float valid = ((unsigned)t < 512u) ? 1.f : 0.f;
                float mu = (lnS[0][R] + lnS[1][R] + lnS[2][R] + lnS[3][R]) * (1.f / 256.f);
                float var = (lnQ[0][R] + lnQ[1][R] + lnQ[2][R] + lnQ[3][R]) * (1.f / 256.f) - mu * mu;
                float rs = rsqrtf(var + 1e-5f);
                #pragma unroll
                for (int ni = 0; ni < 4; ++ni) {
                    int col = wni * 64 + ni * 16 + lr;
                    float hv = ((acc[mi][ni][r] - mu) * rs * gcol[ni] + becol[ni]) * valid;
                    H[R * 256 + (col ^ ((R & 7) << 3))] = f2bf(hv);
                }
            }
        __syncthreads();   // H complete; conv2 tile 0 already in flight
    }

    // ========== CONV2: reads H + pipelined global W, no barriers ==========
    f32x4 acc2[3][4] = {};
    #pragma unroll
    for (int h = 0; h < 4; ++h) {
        #pragma unroll
        for (int j = 0; j < 6; ++j) {
            const int jj = h * 6 + j;             // compile-time
            const int kk = j >> 1, cbl = j & 1;
            if (jj < 23) {
                const int jn = jj + 1;
                const int hn = jn / 6, jn6 = jn % 6;
                LOADW(bw[(jn) & 1], w2p, (jn6 >> 1) * 8 + hn * 2 + (jn6 & 1));
            }
            bf16x8 af[3];
            #pragma unroll
            for (int mi = 0; mi < 3; ++mi) {
                int tr = wmi * 48 + mi * 16 + lr + kk - 1;   // H row, clamp
                int trc = tr < 0 ? 0 : (tr > 95 ? 95 : tr);  // only discarded rows
                af[mi] = *reinterpret_cast<const bf16x8*>(
                    &H[trc * 256 + ((h * 64 + cbl * 32 + grp * 8) ^ ((trc & 7) << 3))]);
            }
            #pragma unroll
            for (int mi = 0; mi < 3; ++mi)
                #pragma unroll
                for (int ni = 0; ni < 4; ++ni)
                    acc2[mi][ni] = __builtin_amdgcn_mfma_f32_16x16x32_bf16(af[mi], bw[jj & 1][ni], acc2[mi][ni], 0, 0, 0);
        }
    }

    // ---- conv2 epilogue: bias+relu, LN, dot lin_w, relu -> dur rows 1..94
    {
        float bcol[4], gcol[4], becol[4], wcol[4];
        #pragma unroll
        for (int ni = 0; ni < 4; ++ni) {
            int col = wni * 64 + ni * 16 + lr;
            bcol[ni] = b2[col]; gcol[ni] = g2[col]; becol[ni] = be2[col]; wcol[ni] = lw[col];
        }
        #pragma unroll
        for (int mi = 0; mi < 3; ++mi)
            #pragma unroll
            for (int ni = 0; ni < 4; ++ni)
                #pragma unroll
                for (int r = 0; r < 4; ++r)
                    acc2[mi][ni][r] = fmaxf(acc2[mi][ni][r] + bcol[ni], 0.f);

        #pragma unroll
        for (int mi = 0; mi < 3; ++mi)
            #pragma unroll
            for (int r = 0; r < 4; ++r) {
                float s = acc2[mi][0][r] + acc2[mi][1][r] + acc2[mi][2][r] + acc2[mi][3][r];
                float q = acc2[mi][0][r] * acc2[mi][0][r] + acc2[mi][1][r] * acc2[mi][1][r]
                        + acc2[mi][2][r] * acc2[mi][2][r] + acc2[mi][3][r] * acc2[mi][3][r];
                #pragma unroll
                for (int off = 1; off < 16; off <<= 1) {
                    s += __shfl_xor(s, off);
                    q += __shfl_xor(q, off);
                }
                if (lr == 0) {
                    int R = wmi * 48 + mi * 16 + grp * 4 + r;
                    lnS[wni][R] = s; lnQ[wni][R] = q;
                }
            }
        __syncthreads();
        #pragma unroll
        for (int mi = 0; mi < 3; ++mi)
            #pragma unroll
            for (int r = 0; r < 4; ++r) {
                int R = wmi * 48 + mi * 16 + grp * 4 + r;
                float mu = (lnS[0][R] + lnS[1][R] + lnS[2][R] + lnS[3][R]) * (1.f / 256.f);
                float var = (lnQ[0][R] + lnQ[1][R] + lnQ[2][R] + lnQ[3][R]) * (1.f / 256.f) - mu * mu;
                float rs = rsqrtf(var + 1e-5f);
                float d = ((acc2[mi][0][r] - mu) * rs * gcol[0] + becol[0]) * wcol[0]
                        + ((acc2[mi][1][r] - mu) * rs * gcol[1] + becol[1]) * wcol[1]
                        + ((acc2[mi][2][r] - mu) * rs * gcol[2] + becol[2]) * wcol[2]
                        + ((acc2[mi][3][r] - mu) * rs * gcol[3] + becol[3]) * wcol[3];
                #pragma unroll
                for (int off = 1; off < 16; off <<= 1) d += __shfl_xor(d, off);
                if (lr == 0) lnD[wni][R] = d;
            }
        __syncthreads();
        if (tid < 96) {
            int R = tid;
            int t = t0 - 1 + R;
            if (R >= 1 && R <= 94 && t < 512) {
                float dd = lnD[0][R] + lnD[1][R] + lnD[2][R] + lnD[3][R] + lb[0];
                dur[(size_t)b * 512 + t] = fmaxf(dd, 0.f);
            }
        }
    }
    #undef LOADW
    #undef STAGE_A
}

extern "C" void kernel_launch(void* const* d_in, const int* in_sizes, int n_in,
                              void* d_out, int out_size, void* d_ws, size_t ws_size,
                              hipStream_t stream) {
    const float* x   = (const float*)d_in[0];
    const float* w1  = (const float*)d_in[1];
    const float* b1  = (const float*)d_in[2];
    const float* g1  = (const float*)d_in[3];
    const float* be1 = (const float*)d_in[4];
    const float* w2  = (const float*)d_in[5];
    const float* b2  = (const float*)d_in[6];
    const float* g2  = (const float*)d_in[7];
    const float* be2 = (const float*)d_in[8];
    const float* lw  = (const float*)d_in[9];
    const float* lb  = (const float*)d_in[10];
    const int* tgt   = (const int*)d_in[11];
    float* out = (float*)d_out;

    const int B = 32, T = 512, C = 256;
    const int rows = B * T;                       // 16384
    const int M = (out_size - rows) / (B * C);    // 3584

    char* ws = (char*)d_ws;
    unsigned short* w1p = (unsigned short*)(ws);              //   393,216 B
    unsigned short* w2p = (unsigned short*)(ws + 393216);     //   393,216 B
    short* idxT         = (short*)(ws + 786432);              //   229,376 B

    prep<<<288, 512, 0, stream>>>(w1, w2, w1p, w2p, tgt, idxT, M);
    // 192 conv blocks (single block-wave; dispatched first) + 1792 gather
    fused<<<1984, 512, 0, stream>>>(x, w1p, b1, g1, be1, w2p, b2, g2, be2,
                                    lw, lb, out + (size_t)B * M * C, idxT, out, M);
}

// Round 24
// 47.724 us; speedup vs baseline: 1.2151x; 1.2151x over previous
//
#include <hip/hip_runtime.h>
#include <hip/hip_bf16.h>

typedef float f32x4 __attribute__((ext_vector_type(4)));
typedef __bf16 bf16x8 __attribute__((ext_vector_type(8)));

static __device__ __forceinline__ unsigned short f2bf(float f) {
    unsigned int u = __float_as_uint(f);
    unsigned int r = (u + 0x7fffu + ((u >> 16) & 1u)) >> 16;   // RNE
    return (unsigned short)r;
}

// ---------------------------------------------------------------------------
// prep: pack conv weights (tile-major MFMA-ready, coalesced reads) +
// cumsum + idx-expand.
// ---------------------------------------------------------------------------
__global__ __launch_bounds__(512) void prep(
    const float* __restrict__ w1, const float* __restrict__ w2,
    unsigned short* __restrict__ w1p, unsigned short* __restrict__ w2p,
    const int* __restrict__ tgt, short* __restrict__ idxT, int M)
{
    int blk = blockIdx.x;
    if (blk < 256) {
        int gi = blk * 512 + threadIdx.x;            // pair index (n,cin)
        const float* w = (gi < 65536) ? w1 : w2;
        unsigned short* wp = (gi < 65536) ? w1p : w2p;
        int p = gi & 65535;
        int n = p >> 8, cin = p & 255;
        const float* src = w + (size_t)p * 3;
        float a[3] = {src[0], src[1], src[2]};
        int nb = n >> 4, nl = n & 15;
        int e = cin & 7, lhi = (cin >> 3) & 3, chi = cin >> 5;
        int base = nb * 512 + (lhi * 16 + nl) * 8 + e;
        #pragma unroll
        for (int kk = 0; kk < 3; ++kk)
            wp[(kk * 8 + chi) * 8192 + base] = f2bf(a[kk]);
    } else {
        __shared__ int s[512];
        int b = blk - 256, tid = threadIdx.x;
        int d = tgt[b * 512 + tid];
        s[tid] = d;
        __syncthreads();
        for (int off = 1; off < 512; off <<= 1) {
            int v = (tid >= off) ? s[tid - off] : 0;
            __syncthreads();
            s[tid] += v;
            __syncthreads();
        }
        int myend = s[tid];
        int mystart = myend - d;
        short* row = idxT + (size_t)b * M;
        for (int p = mystart; p < myend; ++p) row[p] = (short)tid;
        __syncthreads();
        int total = s[511];
        for (int p = total + tid; p < M; p += 512) row[p] = (short)-1;
    }
}

// ---------------------------------------------------------------------------
// Fused conv1+conv2 (halo recompute, H in LDS, W-frags from global/L2 with
// explicit 2-deep register double-buffer) + full gather.  LDS = 44.5 KB.
// ---------------------------------------------------------------------------
__global__ __launch_bounds__(512, 2) void fused(
    const float* __restrict__ x,
    const unsigned short* __restrict__ w1p, const float* __restrict__ b1,
    const float* __restrict__ g1, const float* __restrict__ be1,
    const unsigned short* __restrict__ w2p, const float* __restrict__ b2,
    const float* __restrict__ g2, const float* __restrict__ be2,
    const float* __restrict__ lw, const float* __restrict__ lb,
    float* __restrict__ dur, const short* __restrict__ idxT,
    float* __restrict__ out, int M)
{
    __shared__ __align__(16) unsigned short H[64 * 256];       // 32,768 B
    __shared__ __align__(16) unsigned short As[2][66 * 32];    //  8,448 B dbuf
    __shared__ float lnS[4][64], lnQ[4][64], lnD[4][64];       //  3,072 B

    const int tid = threadIdx.x;
    const int lane = tid & 63;
    const int wv = tid >> 6;

    if (blockIdx.x >= 288) {
        // ---- gather: 64 rows, idx lookup, plain stores
        int gid = blockIdx.x - 288;
        int b = gid / 56;
        int r0 = (gid - b * 56) * 64;
        const short* row = idxT + (size_t)b * M;
        int id[8];
        #pragma unroll
        for (int i = 0; i < 8; ++i) id[i] = row[r0 + i * 8 + wv];
        #pragma unroll
        for (int i = 0; i < 8; ++i) {
            int m = r0 + i * 8 + wv;
            float4 v = make_float4(0.f, 0.f, 0.f, 0.f);
            if (id[i] >= 0)
                v = *reinterpret_cast<const float4*>(x + ((size_t)(b * 512 + id[i])) * 256 + lane * 4);
            *reinterpret_cast<float4*>(out + ((size_t)b * M + m) * 256 + lane * 4) = v;
        }
        return;
    }

    const int wmi = wv >> 2, wni = wv & 3;
    const int grp = lane >> 4, lr = lane & 15;
    const int b = blockIdx.x / 9;
    const int t0 = (blockIdx.x - b * 9) * 62;     // output window [t0, t0+62)

    // per-lane W-frag base offset (ushorts) within a tile
    const int wfoff = (wni * 4) * 512 + lane * 8;

    #define LOADW(dst, wp, ktg) do {                                           \
        const unsigned short* _p = (wp) + (size_t)(ktg) * 8192 + wfoff;        \
        dst[0] = *reinterpret_cast<const bf16x8*>(_p);                         \
        dst[1] = *reinterpret_cast<const bf16x8*>(_p + 512);                   \
        dst[2] = *reinterpret_cast<const bf16x8*>(_p + 1024);                  \
        dst[3] = *reinterpret_cast<const bf16x8*>(_p + 1536);                  \
    } while (0)

    // stage cin-eighth cb of x window into As[buf] (528 float4 chunks)
    #define STAGE_A(cb, buf) do {                                              \
        _Pragma("unroll")                                                      \
        for (int _i = 0; _i < 2; ++_i) {                                       \
            int _cc = _i * 512 + tid;                                          \
            if (_cc < 66 * 8) {                                                \
                int _row = _cc >> 3, _ql = _cc & 7;                            \
                int _tt = t0 - 2 + _row;                                       \
                ushort4 _o = make_ushort4(0, 0, 0, 0);                         \
                if ((unsigned)_tt < 512u) {                                    \
                    float4 _v = *reinterpret_cast<const float4*>(              \
                        x + ((size_t)(b * 512 + _tt)) * 256 + (cb) * 32 + _ql * 4); \
                    _o.x = f2bf(_v.x); _o.y = f2bf(_v.y);                      \
                    _o.z = f2bf(_v.z); _o.w = f2bf(_v.w);                      \
                }                                                              \
                *reinterpret_cast<ushort4*>(                                   \
                    &As[buf][_row * 32 + ((_ql * 4) ^ ((_row & 3) << 3))]) = _o; \
            }                                                                  \
        }                                                                      \
    } while (0)

    // ===================== CONV1: h1[t0-1 .. t0+62] -> H =====================
    f32x4 acc[2][4] = {};
    bf16x8 bw[2][4];                              // 2-deep W-frag pipeline
    STAGE_A(0, 0);
    LOADW(bw[0], w1p, 0);                         // jj=0: kk=0, cb=0 -> ktg 0
    __syncthreads();
    #pragma unroll
    for (int cb = 0; cb < 8; ++cb) {              // cin eighth [cb*32, +32)
        if (cb < 7) STAGE_A(cb + 1, (cb + 1) & 1);   // prefetch next eighth
        #pragma unroll
        for (int kk = 0; kk < 3; ++kk) {
            const int jj = cb * 3 + kk;           // compile-time (both unrolled)
            // prefetch next W tile into the other buffer
            if (jj < 23) {
                const int jn = jj + 1;
                LOADW(bw[jn & 1], w1p, (jn % 3) * 8 + (jn / 3));
            } else {
                LOADW(bw[0], w2p, 0);             // conv2 tile 0 (hides under epilogue)
            }
            bf16x8 af[2];
            #pragma unroll
            for (int mi = 0; mi < 2; ++mi) {
                int tr = wmi * 32 + mi * 16 + lr + kk;
                af[mi] = *reinterpret_cast<const bf16x8*>(
                    &As[cb & 1][tr * 32 + ((grp * 8) ^ ((tr & 3) << 3))]);
            }
            #pragma unroll
            for (int mi = 0; mi < 2; ++mi)
                #pragma unroll
                for (int ni = 0; ni < 4; ++ni)
                    acc[mi][ni] = __builtin_amdgcn_mfma_f32_16x16x32_bf16(af[mi], bw[jj & 1][ni], acc[mi][ni], 0, 0, 0);
        }
        __syncthreads();                          // stage(cb+1) stores + As reads done
    }

    // ---- conv1 epilogue: bias+relu, LN, store H (bf16, swizzled, zero-guard)
    {
        float bcol[4], gcol[4], becol[4];
        #pragma unroll
        for (int ni = 0; ni < 4; ++ni) {
            int col = wni * 64 + ni * 16 + lr;
            bcol[ni] = b1[col]; gcol[ni] = g1[col]; becol[ni] = be1[col];
        }
        #pragma unroll
        for (int mi = 0; mi < 2; ++mi)
            #pragma unroll
            for (int ni = 0; ni < 4; ++ni)
                #pragma unroll
                for (int r = 0; r < 4; ++r)
                    acc[mi][ni][r] = fmaxf(acc[mi][ni][r] + bcol[ni], 0.f);

        #pragma unroll
        for (int mi = 0; mi < 2; ++mi)
            #pragma unroll
            for (int r = 0; r < 4; ++r) {
                float s = acc[mi][0][r] + acc[mi][1][r] + acc[mi][2][r] + acc[mi][3][r];
                float q = acc[mi][0][r] * acc[mi][0][r] + acc[mi][1][r] * acc[mi][1][r]
                        + acc[mi][2][r] * acc[mi][2][r] + acc[mi][3][r] * acc[mi][3][r];
                #pragma unroll
                for (int off = 1; off < 16; off <<= 1) {
                    s += __shfl_xor(s, off);
                    q += __shfl_xor(q, off);
                }
                if (lr == 0) {
                    int R = wmi * 32 + mi * 16 + grp * 4 + r;
                    lnS[wni][R] = s; lnQ[wni][R] = q;
                }
            }
        __syncthreads();
        #pragma unroll
        for (int mi = 0; mi < 2; ++mi)
            #pragma unroll
            for (int r = 0; r < 4; ++r) {
                int R = wmi * 32 + mi * 16 + grp * 4 + r;    // h1 row t = t0-1+R
                int t = t0 - 1 + R;
                float valid = ((unsigned)t < 512u) ? 1.f : 0.f;
                float mu = (lnS[0][R] + lnS[1][R] + lnS[2][R] + lnS[3][R]) * (1.f / 256.f);
                float var = (lnQ[0][R] + lnQ[1][R] + lnQ[2][R] + lnQ[3][R]) * (1.f / 256.f) - mu * mu;
                float rs = rsqrtf(var + 1e-5f);
                #pragma unroll
                for (int ni = 0; ni < 4; ++ni) {
                    int col = wni * 64 + ni * 16 + lr;
                    float hv = ((acc[mi][ni][r] - mu) * rs * gcol[ni] + becol[ni]) * valid;
                    H[R * 256 + (col ^ ((R & 7) << 3))] = f2bf(hv);
                }
            }
        __syncthreads();   // H complete
    }

    // ========== CONV2: reads H + pipelined global W, no barriers ==========
    f32x4 acc2[2][4] = {};
    #pragma unroll
    for (int h = 0; h < 4; ++h) {
        #pragma unroll
        for (int j = 0; j < 6; ++j) {
            const int jj = h * 6 + j;             // compile-time
            const int kk = j >> 1, cbl = j & 1;
            if (jj < 23) {
                const int jn = jj + 1;
                const int hn = jn / 6, jn6 = jn % 6;
                LOADW(bw[(jn) & 1], w2p, (jn6 >> 1) * 8 + hn * 2 + (jn6 & 1));
            }
            bf16x8 af[2];
            #pragma unroll
            for (int mi = 0; mi < 2; ++mi) {
                int tr = wmi * 32 + mi * 16 + lr + kk - 1;   // H row, clamp
                int trc = tr < 0 ? 0 : (tr > 63 ? 63 : tr);  // only discarded rows
                af[mi] = *reinterpret_cast<const bf16x8*>(
                    &H[trc * 256 + ((h * 64 + cbl * 32 + grp * 8) ^ ((trc & 7) << 3))]);
            }
            #pragma unroll
            for (int mi = 0; mi < 2; ++mi)
                #pragma unroll
                for (int ni = 0; ni < 4; ++ni)
                    acc2[mi][ni] = __builtin_amdgcn_mfma_f32_16x16x32_bf16(af[mi], bw[jj & 1][ni], acc2[mi][ni], 0, 0, 0);
        }
    }

    // ---- conv2 epilogue: bias+relu, LN, dot lin_w, relu -> dur rows 1..62
    {
        float bcol[4], gcol[4], becol[4], wcol[4];
        #pragma unroll
        for (int ni = 0; ni < 4; ++ni) {
            int col = wni * 64 + ni * 16 + lr;
            bcol[ni] = b2[col]; gcol[ni] = g2[col]; becol[ni] = be2[col]; wcol[ni] = lw[col];
        }
        #pragma unroll
        for (int mi = 0; mi < 2; ++mi)
            #pragma unroll
            for (int ni = 0; ni < 4; ++ni)
                #pragma unroll
                for (int r = 0; r < 4; ++r)
                    acc2[mi][ni][r] = fmaxf(acc2[mi][ni][r] + bcol[ni], 0.f);

        #pragma unroll
        for (int mi = 0; mi < 2; ++mi)
            #pragma unroll
            for (int r = 0; r < 4; ++r) {
                float s = acc2[mi][0][r] + acc2[mi][1][r] + acc2[mi][2][r] + acc2[mi][3][r];
                float q = acc2[mi][0][r] * acc2[mi][0][r] + acc2[mi][1][r] * acc2[mi][1][r]
                        + acc2[mi][2][r] * acc2[mi][2][r] + acc2[mi][3][r] * acc2[mi][3][r];
                #pragma unroll
                for (int off = 1; off < 16; off <<= 1) {
                    s += __shfl_xor(s, off);
                    q += __shfl_xor(q, off);
                }
                if (lr == 0) {
                    int R = wmi * 32 + mi * 16 + grp * 4 + r;
                    lnS[wni][R] = s; lnQ[wni][R] = q;
                }
            }
        __syncthreads();
        #pragma unroll
        for (int mi = 0; mi < 2; ++mi)
            #pragma unroll
            for (int r = 0; r < 4; ++r) {
                int R = wmi * 32 + mi * 16 + grp * 4 + r;
                float mu = (lnS[0][R] + lnS[1][R] + lnS[2][R] + lnS[3][R]) * (1.f / 256.f);
                float var = (lnQ[0][R] + lnQ[1][R] + lnQ[2][R] + lnQ[3][R]) * (1.f / 256.f) - mu * mu;
                float rs = rsqrtf(var + 1e-5f);
                float d = ((acc2[mi][0][r] - mu) * rs * gcol[0] + becol[0]) * wcol[0]
                        + ((acc2[mi][1][r] - mu) * rs * gcol[1] + becol[1]) * wcol[1]
                        + ((acc2[mi][2][r] - mu) * rs * gcol[2] + becol[2]) * wcol[2]
                        + ((acc2[mi][3][r] - mu) * rs * gcol[3] + becol[3]) * wcol[3];
                #pragma unroll
                for (int off = 1; off < 16; off <<= 1) d += __shfl_xor(d, off);
                if (lr == 0) lnD[wni][R] = d;
            }
        __syncthreads();
        if (tid < 64) {
            int R = tid;
            int t = t0 - 1 + R;
            if (R >= 1 && R <= 62 && t < 512) {
                float dd = lnD[0][R] + lnD[1][R] + lnD[2][R] + lnD[3][R] + lb[0];
                dur[(size_t)b * 512 + t] = fmaxf(dd, 0.f);
            }
        }
    }
    #undef LOADW
    #undef STAGE_A
}

extern "C" void kernel_launch(void* const* d_in, const int* in_sizes, int n_in,
                              void* d_out, int out_size, void* d_ws, size_t ws_size,
                              hipStream_t stream) {
    const float* x   = (const float*)d_in[0];
    const float* w1  = (const float*)d_in[1];
    const float* b1  = (const float*)d_in[2];
    const float* g1  = (const float*)d_in[3];
    const float* be1 = (const float*)d_in[4];
    const float* w2  = (const float*)d_in[5];
    const float* b2  = (const float*)d_in[6];
    const float* g2  = (const float*)d_in[7];
    const float* be2 = (const float*)d_in[8];
    const float* lw  = (const float*)d_in[9];
    const float* lb  = (const float*)d_in[10];
    const int* tgt   = (const int*)d_in[11];
    float* out = (float*)d_out;

    const int B = 32, T = 512, C = 256;
    const int rows = B * T;                       // 16384
    const int M = (out_size - rows) / (B * C);    // 3584

    char* ws = (char*)d_ws;
    unsigned short* w1p = (unsigned short*)(ws);              //   393,216 B
    unsigned short* w2p = (unsigned short*)(ws + 393216);     //   393,216 B
    short* idxT         = (short*)(ws + 786432);              //   229,376 B

    prep<<<288, 512, 0, stream>>>(w1, w2, w1p, w2p, tgt, idxT, M);
    // 288 fused-conv blocks (dispatched first) + 1792 gather blocks
    fused<<<2080, 512, 0, stream>>>(x, w1p, b1, g1, be1, w2p, b2, g2, be2,
                                    lw, lb, out + (size_t)B * M * C, idxT, out, M);
}